// Round 9
// baseline (348.498 us; speedup 1.0000x reference)
//
#include <hip/hip_runtime.h>
#include <hip/hip_bf16.h>

#define NODES 8192
#define INF_ 256
#define OUTF 128
#define LRALPHA 0.02f

typedef __bf16 bf16;
typedef bf16 bf16x8 __attribute__((ext_vector_type(8)));
typedef float f32x4 __attribute__((ext_vector_type(4)));
typedef float f32x16 __attribute__((ext_vector_type(16)));
typedef int i32x4 __attribute__((ext_vector_type(4)));

// ---------------- Kernel 1: Wh = x@W1 + b1 -> WhbF (MFMA fragment order) + exp arrays ----
__global__ __launch_bounds__(256) void gat_prep_r9(
    const float* __restrict__ x, const float* __restrict__ W1,
    const float* __restrict__ b1, const float* __restrict__ a,
    const float* __restrict__ b_att,
    bf16* __restrict__ WhbF, float* __restrict__ E1,
    float* __restrict__ E2, float* __restrict__ F1, float* __restrict__ F2)
{
    __shared__ float xsT[64][36];    // [k][row], padded
    __shared__ float ws1[64][132];   // [k][col], padded
    __shared__ float wh[32][128];    // Wh tile f32

    const int t = threadIdx.x;
    const int rbase = blockIdx.x * 32;
    const int tr = t >> 5;   // 0..7  -> rows tr*4..+3
    const int tc = t & 31;   // 0..31 -> cols tc*4..+3

    f32x4 acc[4];
    f32x4 bias = *(const f32x4*)&b1[tc * 4];
#pragma unroll
    for (int i = 0; i < 4; ++i) acc[i] = bias;

    for (int kt = 0; kt < 4; ++kt) {
        const int kb = kt * 64;
        {   // stage x tile transposed: xsT[k][r] = x[rbase+r][kb+k]
            int r = t >> 3;            // 0..31
            int kq = (t & 7) * 8;      // 0..56
            f32x4 v0 = *(const f32x4*)&x[(size_t)(rbase + r) * INF_ + kb + kq];
            f32x4 v1 = *(const f32x4*)&x[(size_t)(rbase + r) * INF_ + kb + kq + 4];
#pragma unroll
            for (int i = 0; i < 4; ++i) xsT[kq + i][r] = v0[i];
#pragma unroll
            for (int i = 0; i < 4; ++i) xsT[kq + 4 + i][r] = v1[i];
        }
        {   // stage W1 tile: ws1[k][c] = W1[kb+k][c]
            int kr = t >> 2;           // 0..63
            int cq = (t & 3) * 32;
#pragma unroll
            for (int i = 0; i < 8; ++i) {
                f32x4 v = *(const f32x4*)&W1[(size_t)(kb + kr) * OUTF + cq + i * 4];
                *(f32x4*)&ws1[kr][cq + i * 4] = v;
            }
        }
        __syncthreads();
        for (int kk = 0; kk < 64; ++kk) {
            f32x4 xa = *(const f32x4*)&xsT[kk][tr * 4];
            f32x4 wb = *(const f32x4*)&ws1[kk][tc * 4];
#pragma unroll
            for (int i = 0; i < 4; ++i)
#pragma unroll
                for (int j = 0; j < 4; ++j)
                    acc[i][j] += xa[i] * wb[j];
        }
        __syncthreads();
    }

#pragma unroll
    for (int i = 0; i < 4; ++i)
        *(f32x4*)&wh[tr * 4 + i][tc * 4] = acc[i];
    __syncthreads();

    if (t < 32) {
        float s1 = 0.f, s2 = 0.f;
        for (int c = 0; c < OUTF; ++c) {
            float v = wh[t][c];
            s1 += v * a[c];
            s2 += v * a[OUTF + c];
        }
        float fsv = s1 + b_att[0];
        int r = rbase + t;
        E1[r] = expf(fsv);
        E2[r] = expf(LRALPHA * fsv);
        F1[r] = expf(s2);
        F2[r] = expf(LRALPHA * s2);
    }

    {   // WhbF fragment writes: thread t -> (kb, fb, c), two lane-halves h
        const int kb = t >> 7;          // 0..1
        const int fb = (t >> 5) & 3;    // 0..3
        const int c  = t & 31;          // feat within fb
        const size_t jblk = (size_t)blockIdx.x * 2 + kb;
#pragma unroll
        for (int h = 0; h < 2; ++h) {
            const int lane = c + h * 32;
            bf16x8 v;
#pragma unroll
            for (int e = 0; e < 8; ++e)
                v[e] = (bf16)wh[kb * 16 + h * 8 + e][fb * 32 + c];
            *(bf16x8*)&WhbF[((jblk * 4 + fb) * 64 + lane) * 8] = v;
        }
    }
}

// ---------------- Kernel 2: FUSED adj-stream + masked softmax + PV (bf16 MFMA) + elu ----
// 16 waves = 16 K-strips of 512 cols; block owns rows rbase..rbase+31.
// adj is read directly (coalesced: lane=column, 256B/row-segment), redistributed to
// the MFMA B-fragment layout via __ballot (bit L = column L). adj batch for col-block
// cb+1 is issued before compute of cb (depth-1). No separate pack pass, no mask buffer.
// Epilogue cascade uses stride-65 slots (conflict-free).
#define DENRED_OFF 0
#define TAB_OFF    2048
#define ZONE_OFF   2048                 // zones alias tables (dead after main loop)
#define SLOT_BYTES 16640                // 64 lanes * 65 f32 * 4B
#define SMEM2_SIZE (2048 + 8 * SLOT_BYTES)   // 135168

__global__ __launch_bounds__(1024, 4) void gat_attn_r9(
    const int* __restrict__ adj,
    const bf16* __restrict__ WhbF,
    const float* __restrict__ E1, const float* __restrict__ E2,
    const float* __restrict__ F1, const float* __restrict__ F2,
    float* __restrict__ out)
{
    extern __shared__ char smem[];
    float* denred = (float*)(smem + DENRED_OFF);
    float* F1t = (float*)(smem + TAB_OFF);             // 8192 f32
    float* F2t = (float*)(smem + TAB_OFF + 32768);     // 8192 f32

    const int tid = threadIdx.x;
    const int lane = tid & 63;
    const int wv = tid >> 6;        // 0..15 : K-strip
    const int rbase = blockIdx.x * 32;
    const int r = lane & 31;
    const int ag = lane >> 5;
    const int agsh = ag * 8;

    {   // stage F1/F2 tables (8 floats per thread per table)
        int i = tid * 8;
        *(f32x4*)&F1t[i]     = *(const f32x4*)&F1[i];
        *(f32x4*)&F1t[i + 4] = *(const f32x4*)&F1[i + 4];
        *(f32x4*)&F2t[i]     = *(const f32x4*)&F2[i];
        *(f32x4*)&F2t[i + 4] = *(const f32x4*)&F2[i + 4];
    }

    const float e1v = E1[rbase + r];
    const float e2v = E2[rbase + r];
    const int j0 = wv * 512;
    const size_t adj_base = (size_t)rbase * NODES + j0 + lane;

    f32x16 acc0, acc1, acc2, acc3;
#pragma unroll
    for (int i = 0; i < 16; ++i) { acc0[i] = 0.f; acc1[i] = 0.f; acc2[i] = 0.f; acc3[i] = 0.f; }
    float den = 0.f;

    __syncthreads();   // tables staged

    // ---- prologue: adj col-block 0 -> myb (64 mask bits for row r, cols j0..j0+63) ----
    unsigned long long myb = 0ull;
    {
        int av[32];
#pragma unroll
        for (int q = 0; q < 32; ++q)
            av[q] = adj[adj_base + (size_t)q * NODES];
#pragma unroll
        for (int q = 0; q < 32; ++q) {
            unsigned long long b = __ballot(av[q] != 0);
            myb = (q == r) ? b : myb;
        }
    }

#pragma unroll 1
    for (int cb = 0; cb < 8; ++cb) {
        // 1) issue adj batch for next col-block (clamped at tail; unused then)
        const int cbn = (cb < 7) ? (cb + 1) : 7;
        int av[32];
#pragma unroll
        for (int q = 0; q < 32; ++q)
            av[q] = adj[adj_base + (size_t)q * NODES + cbn * 64];

        // 2) compute 4 x 16-col iterations on current myb
#pragma unroll
        for (int i16 = 0; i16 < 4; ++i16) {
            const int s = cb * 4 + i16;                  // 0..31
            const size_t fbase = ((size_t)(wv * 32 + s) * 4) * 512 + lane * 8;
            bf16x8 wc0 = *(const bf16x8*)&WhbF[fbase];
            bf16x8 wc1 = *(const bf16x8*)&WhbF[fbase + 512];
            bf16x8 wc2 = *(const bf16x8*)&WhbF[fbase + 1024];
            bf16x8 wc3 = *(const bf16x8*)&WhbF[fbase + 1536];

            const int jl = j0 + s * 16 + agsh;
            f32x4 g1a = *(const f32x4*)&F1t[jl];
            f32x4 g1b = *(const f32x4*)&F1t[jl + 4];
            f32x4 g2a = *(const f32x4*)&F2t[jl];
            f32x4 g2b = *(const f32x4*)&F2t[jl + 4];

            const unsigned int b8 =
                (unsigned int)(myb >> (i16 * 16 + agsh)) & 0xffu;

            bf16x8 wb;
#pragma unroll
            for (int jj = 0; jj < 4; ++jj) {
                float tv = e1v * g1a[jj];                 // e^s ; s>0 <=> tv>1
                float w = tv > 1.f ? tv : e2v * g2a[jj];
                w = (b8 & (1u << jj)) ? w : 0.f;
                den += w;
                wb[jj] = (bf16)w;
            }
#pragma unroll
            for (int jj = 0; jj < 4; ++jj) {
                float tv = e1v * g1b[jj];
                float w = tv > 1.f ? tv : e2v * g2b[jj];
                w = (b8 & (16u << jj)) ? w : 0.f;
                den += w;
                wb[4 + jj] = (bf16)w;
            }

            acc0 = __builtin_amdgcn_mfma_f32_32x32x16_bf16(wc0, wb, acc0, 0, 0, 0);
            acc1 = __builtin_amdgcn_mfma_f32_32x32x16_bf16(wc1, wb, acc1, 0, 0, 0);
            acc2 = __builtin_amdgcn_mfma_f32_32x32x16_bf16(wc2, wb, acc2, 0, 0, 0);
            acc3 = __builtin_amdgcn_mfma_f32_32x32x16_bf16(wc3, wb, acc3, 0, 0, 0);
        }

        // 3) ballots for next col-block
        if (cb < 7) {
#pragma unroll
            for (int q = 0; q < 32; ++q) {
                unsigned long long b = __ballot(av[q] != 0);
                myb = (q == r) ? b : myb;
            }
        }
    }

    den += __shfl_xor(den, 32);

    __syncthreads();   // main loop done everywhere; tables dead, zones live
    if (lane < 32) denred[wv * 32 + r] = den;

    auto dump = [&](int slot) {
        float* z = (float*)(smem + ZONE_OFF + (size_t)slot * SLOT_BYTES) + lane * 65;
        *(f32x16*)(z)      = acc0;
        *(f32x16*)(z + 16) = acc1;
        *(f32x16*)(z + 32) = acc2;
        *(f32x16*)(z + 48) = acc3;
    };
    auto take = [&](int slot) {
        const float* z = (const float*)(smem + ZONE_OFF + (size_t)slot * SLOT_BYTES) + lane * 65;
        f32x16 v0 = *(const f32x16*)(z);
        f32x16 v1 = *(const f32x16*)(z + 16);
        f32x16 v2 = *(const f32x16*)(z + 32);
        f32x16 v3 = *(const f32x16*)(z + 48);
#pragma unroll
        for (int i = 0; i < 16; ++i) {
            acc0[i] += v0[i]; acc1[i] += v1[i]; acc2[i] += v2[i]; acc3[i] += v3[i];
        }
    };

    if (wv >= 8) dump(wv - 8);
    __syncthreads();
    if (wv < 8) take(wv);
    __syncthreads();
    if (wv >= 4 && wv < 8) dump(wv - 4);
    __syncthreads();
    if (wv < 4) take(wv);
    __syncthreads();
    if (wv == 2 || wv == 3) dump(wv - 2);
    __syncthreads();
    if (wv < 2) take(wv);
    __syncthreads();
    if (wv == 1) dump(0);
    __syncthreads();

    if (wv == 0) {
        take(0);
        float ds = 0.f;
#pragma unroll
        for (int w = 0; w < 16; ++w) ds += denred[w * 32 + r];
        const float inv = 1.f / ds;
        const size_t orow = (size_t)(rbase + r) * OUTF;
#pragma unroll
        for (int fb = 0; fb < 4; ++fb) {
            const f32x16* A = (fb == 0) ? &acc0 : (fb == 1) ? &acc1 : (fb == 2) ? &acc2 : &acc3;
#pragma unroll
            for (int u = 0; u < 4; ++u) {
                f32x4 o;
#pragma unroll
                for (int e = 0; e < 4; ++e) {
                    float v = (*A)[4 * u + e] * inv;
                    o[e] = v > 0.f ? v : expm1f(v);
                }
                *(f32x4*)&out[orow + fb * 32 + 8 * u + 4 * ag] = o;
            }
        }
    }
}

extern "C" void kernel_launch(void* const* d_in, const int* in_sizes, int n_in,
                              void* d_out, int out_size, void* d_ws, size_t ws_size,
                              hipStream_t stream) {
    const float* x     = (const float*)d_in[0];
    const int*   adj   = (const int*)d_in[1];
    const float* W1    = (const float*)d_in[2];
    const float* b1    = (const float*)d_in[3];
    const float* a     = (const float*)d_in[4];
    const float* b_att = (const float*)d_in[5];
    float* out = (float*)d_out;

    char* ws = (char*)d_ws;
    bf16* WhbF = (bf16*)ws;                                   // 2 MB
    float* E1 = (float*)(ws + (size_t)2 * 1024 * 1024);
    float* E2 = E1 + NODES;
    float* F1 = E2 + NODES;
    float* F2 = F1 + NODES;

    hipLaunchKernelGGL(gat_prep_r9, dim3(NODES / 32), dim3(256), 0, stream,
                       x, W1, b1, a, b_att, WhbF, E1, E2, F1, F2);

    hipLaunchKernelGGL(gat_attn_r9, dim3(NODES / 32), dim3(1024), SMEM2_SIZE, stream,
                       adj, WhbF, E1, E2, F1, F2, out);
}

// Round 10
// 160.441 us; speedup vs baseline: 2.1721x; 2.1721x over previous
//
#include <hip/hip_runtime.h>
#include <hip/hip_bf16.h>

#define NODES 8192
#define INF_ 256
#define OUTF 128
#define LRALPHA 0.02f

typedef __bf16 bf16;
typedef bf16 bf16x8 __attribute__((ext_vector_type(8)));
typedef float f32x4 __attribute__((ext_vector_type(4)));
typedef float f32x16 __attribute__((ext_vector_type(16)));
typedef int i32x4 __attribute__((ext_vector_type(4)));

// ---------------- Kernel 0: bitpack adj (256MB int32 -> 8MB bitmask), single pass ----------
// Proven 43.6 us @ 5.87 TB/s (r7 x5 instrumentation). Byte b of mask covers cols 8b..8b+7
// of row 8b/1024 (row-major, 1024B/row, LSB-first).
__global__ __launch_bounds__(256) void gat_pack_r10(
    const i32x4* __restrict__ adj4, unsigned char* __restrict__ mask8)
{
    const unsigned int tid = threadIdx.x;
    const size_t t = (size_t)blockIdx.x * 256 + tid;
    i32x4 v = adj4[t];
    unsigned int nib = (v[0] != 0 ? 1u : 0u) | (v[1] != 0 ? 2u : 0u)
                     | (v[2] != 0 ? 4u : 0u) | (v[3] != 0 ? 8u : 0u);
    unsigned int other = (unsigned int)__shfl_xor((int)nib, 1);
    if ((tid & 1) == 0) mask8[t >> 1] = (unsigned char)(nib | (other << 4));
}

// ---------------- Kernel 1: Wh = x@W1 + b1 -> WhbF (MFMA fragment order) + exp arrays ----
__global__ __launch_bounds__(256) void gat_prep_r10(
    const float* __restrict__ x, const float* __restrict__ W1,
    const float* __restrict__ b1, const float* __restrict__ a,
    const float* __restrict__ b_att,
    bf16* __restrict__ WhbF, float* __restrict__ E1,
    float* __restrict__ E2, float* __restrict__ F1, float* __restrict__ F2)
{
    __shared__ float xsT[64][36];    // [k][row], padded
    __shared__ float ws1[64][132];   // [k][col], padded
    __shared__ float wh[32][128];    // Wh tile f32

    const int t = threadIdx.x;
    const int rbase = blockIdx.x * 32;
    const int tr = t >> 5;   // 0..7  -> rows tr*4..+3
    const int tc = t & 31;   // 0..31 -> cols tc*4..+3

    f32x4 acc[4];
    f32x4 bias = *(const f32x4*)&b1[tc * 4];
#pragma unroll
    for (int i = 0; i < 4; ++i) acc[i] = bias;

    for (int kt = 0; kt < 4; ++kt) {
        const int kb = kt * 64;
        {   // stage x tile transposed: xsT[k][r] = x[rbase+r][kb+k]
            int r = t >> 3;            // 0..31
            int kq = (t & 7) * 8;      // 0..56
            f32x4 v0 = *(const f32x4*)&x[(size_t)(rbase + r) * INF_ + kb + kq];
            f32x4 v1 = *(const f32x4*)&x[(size_t)(rbase + r) * INF_ + kb + kq + 4];
#pragma unroll
            for (int i = 0; i < 4; ++i) xsT[kq + i][r] = v0[i];
#pragma unroll
            for (int i = 0; i < 4; ++i) xsT[kq + 4 + i][r] = v1[i];
        }
        {   // stage W1 tile: ws1[k][c] = W1[kb+k][c]
            int kr = t >> 2;           // 0..63
            int cq = (t & 3) * 32;
#pragma unroll
            for (int i = 0; i < 8; ++i) {
                f32x4 v = *(const f32x4*)&W1[(size_t)(kb + kr) * OUTF + cq + i * 4];
                *(f32x4*)&ws1[kr][cq + i * 4] = v;
            }
        }
        __syncthreads();
        for (int kk = 0; kk < 64; ++kk) {
            f32x4 xa = *(const f32x4*)&xsT[kk][tr * 4];
            f32x4 wb = *(const f32x4*)&ws1[kk][tc * 4];
#pragma unroll
            for (int i = 0; i < 4; ++i)
#pragma unroll
                for (int j = 0; j < 4; ++j)
                    acc[i][j] += xa[i] * wb[j];
        }
        __syncthreads();
    }

#pragma unroll
    for (int i = 0; i < 4; ++i)
        *(f32x4*)&wh[tr * 4 + i][tc * 4] = acc[i];
    __syncthreads();

    if (t < 32) {
        float s1 = 0.f, s2 = 0.f;
        for (int c = 0; c < OUTF; ++c) {
            float v = wh[t][c];
            s1 += v * a[c];
            s2 += v * a[OUTF + c];
        }
        float fsv = s1 + b_att[0];
        int r = rbase + t;
        E1[r] = expf(fsv);
        E2[r] = expf(LRALPHA * fsv);
        F1[r] = expf(s2);
        F2[r] = expf(LRALPHA * s2);
    }

    {   // WhbF fragment writes: thread t -> (kb, fb, c), two lane-halves h
        const int kb = t >> 7;          // 0..1
        const int fb = (t >> 5) & 3;    // 0..3
        const int c  = t & 31;          // feat within fb
        const size_t jblk = (size_t)blockIdx.x * 2 + kb;
#pragma unroll
        for (int h = 0; h < 2; ++h) {
            const int lane = c + h * 32;
            bf16x8 v;
#pragma unroll
            for (int e = 0; e < 8; ++e)
                v[e] = (bf16)wh[kb * 16 + h * 8 + e][fb * 32 + c];
            *(bf16x8*)&WhbF[((jblk * 4 + fb) * 64 + lane) * 8] = v;
        }
    }
}

// ---------------- Kernel 2: mask-based masked softmax + PV (bf16 MFMA) + elu ----------
// 512 thr = 8 waves (launch_bounds(512,2): 256-VGPR budget, 1 block/CU). Each wave:
// strip of 1024 cols = 64 iters x 16 cols. Depth-1 register prefetch of WhbF fragments,
// LDS g-tables, and the mask u64 (from the 8MB L2-resident mask buffer). acc = 32x128.
#define DENRED_OFF 0
#define TAB_OFF    1024
#define ZONE_OFF   1024                 // zones alias tables (dead after main loop)
#define SLOT_BYTES 16640                // 64 lanes * 65 f32 * 4B
#define SMEM2_SIZE (1024 + 4 * SLOT_BYTES)   // 67584

__global__ __launch_bounds__(512, 2) void gat_attn_r10(
    const unsigned long long* __restrict__ m64,
    const bf16* __restrict__ WhbF,
    const float* __restrict__ E1, const float* __restrict__ E2,
    const float* __restrict__ F1, const float* __restrict__ F2,
    float* __restrict__ out)
{
    extern __shared__ char smem[];
    float* denred = (float*)(smem + DENRED_OFF);       // [8][32]
    float* F1t = (float*)(smem + TAB_OFF);             // 8192 f32
    float* F2t = (float*)(smem + TAB_OFF + 32768);     // 8192 f32

    const int tid = threadIdx.x;
    const int lane = tid & 63;
    const int wv = tid >> 6;        // 0..7 : K-strip of 1024 cols
    const int rbase = blockIdx.x * 32;
    const int r = lane & 31;
    const int ag = lane >> 5;
    const int agsh = ag * 8;

    {   // stage F1/F2 tables (16 floats per thread per table)
        int i = tid * 16;
#pragma unroll
        for (int q = 0; q < 4; ++q) {
            *(f32x4*)&F1t[i + q * 4] = *(const f32x4*)&F1[i + q * 4];
            *(f32x4*)&F2t[i + q * 4] = *(const f32x4*)&F2[i + q * 4];
        }
    }

    const float e1v = E1[rbase + r];
    const float e2v = E2[rbase + r];
    const int j0 = wv * 1024;
    const size_t mbase = (size_t)(rbase + r) * 128 + wv * 16;   // u64 index

    f32x16 acc0, acc1, acc2, acc3;
#pragma unroll
    for (int i = 0; i < 16; ++i) { acc0[i] = 0.f; acc1[i] = 0.f; acc2[i] = 0.f; acc3[i] = 0.f; }
    float den = 0.f;

    __syncthreads();   // tables staged

    // ---- prologue: mask cb0/cb1; fragments + g-tables for s=0 ----
    unsigned long long myb = m64[mbase];
    unsigned long long mybn = m64[mbase + 1];
    bf16x8 wc0, wc1, wc2, wc3;
    f32x4 c1a, c1b, c2a, c2b;
    {
        const size_t fb0 = (size_t)(wv * 64 + 0) * 4 * 512 + lane * 8;
        wc0 = *(const bf16x8*)&WhbF[fb0];
        wc1 = *(const bf16x8*)&WhbF[fb0 + 512];
        wc2 = *(const bf16x8*)&WhbF[fb0 + 1024];
        wc3 = *(const bf16x8*)&WhbF[fb0 + 1536];
        const int jl = j0 + agsh;
        c1a = *(const f32x4*)&F1t[jl];
        c1b = *(const f32x4*)&F1t[jl + 4];
        c2a = *(const f32x4*)&F2t[jl];
        c2b = *(const f32x4*)&F2t[jl + 4];
    }

#pragma unroll 1
    for (int cb = 0; cb < 16; ++cb) {
#pragma unroll
        for (int i4 = 0; i4 < 4; ++i4) {
            const int s = cb * 4 + i4;
            const int sn = (s < 63) ? s + 1 : 63;

            // issue next-iteration loads (VMEM fragments + LDS tables)
            const size_t fbn = (size_t)(wv * 64 + sn) * 4 * 512 + lane * 8;
            bf16x8 wn0 = *(const bf16x8*)&WhbF[fbn];
            bf16x8 wn1 = *(const bf16x8*)&WhbF[fbn + 512];
            bf16x8 wn2 = *(const bf16x8*)&WhbF[fbn + 1024];
            bf16x8 wn3 = *(const bf16x8*)&WhbF[fbn + 1536];
            const int jn = j0 + sn * 16 + agsh;
            f32x4 n1a = *(const f32x4*)&F1t[jn];
            f32x4 n1b = *(const f32x4*)&F1t[jn + 4];
            f32x4 n2a = *(const f32x4*)&F2t[jn];
            f32x4 n2b = *(const f32x4*)&F2t[jn + 4];

            // compute weights for current 16 cols
            const unsigned int b8 = (unsigned int)(myb >> (i4 * 16 + agsh)) & 0xffu;
            bf16x8 wb;
#pragma unroll
            for (int jj = 0; jj < 4; ++jj) {
                float tv = e1v * c1a[jj];                 // e^s ; s>0 <=> tv>1
                float w = tv > 1.f ? tv : e2v * c2a[jj];
                w = (b8 & (1u << jj)) ? w : 0.f;
                den += w;
                wb[jj] = (bf16)w;
            }
#pragma unroll
            for (int jj = 0; jj < 4; ++jj) {
                float tv = e1v * c1b[jj];
                float w = tv > 1.f ? tv : e2v * c2b[jj];
                w = (b8 & (16u << jj)) ? w : 0.f;
                den += w;
                wb[4 + jj] = (bf16)w;
            }

            acc0 = __builtin_amdgcn_mfma_f32_32x32x16_bf16(wc0, wb, acc0, 0, 0, 0);
            acc1 = __builtin_amdgcn_mfma_f32_32x32x16_bf16(wc1, wb, acc1, 0, 0, 0);
            acc2 = __builtin_amdgcn_mfma_f32_32x32x16_bf16(wc2, wb, acc2, 0, 0, 0);
            acc3 = __builtin_amdgcn_mfma_f32_32x32x16_bf16(wc3, wb, acc3, 0, 0, 0);

            wc0 = wn0; wc1 = wn1; wc2 = wn2; wc3 = wn3;
            c1a = n1a; c1b = n1b; c2a = n2a; c2b = n2b;
        }
        myb = mybn;
        mybn = m64[mbase + ((cb < 14) ? (cb + 2) : 15)];
    }

    den += __shfl_xor(den, 32);

    __syncthreads();   // main loop done everywhere; tables dead, zones live
    if (lane < 32) denred[wv * 32 + r] = den;

    auto dump = [&](int slot) {
        float* z = (float*)(smem + ZONE_OFF + (size_t)slot * SLOT_BYTES) + lane * 65;
        *(f32x16*)(z)      = acc0;
        *(f32x16*)(z + 16) = acc1;
        *(f32x16*)(z + 32) = acc2;
        *(f32x16*)(z + 48) = acc3;
    };
    auto take = [&](int slot) {
        const float* z = (const float*)(smem + ZONE_OFF + (size_t)slot * SLOT_BYTES) + lane * 65;
        f32x16 v0 = *(const f32x16*)(z);
        f32x16 v1 = *(const f32x16*)(z + 16);
        f32x16 v2 = *(const f32x16*)(z + 32);
        f32x16 v3 = *(const f32x16*)(z + 48);
#pragma unroll
        for (int i = 0; i < 16; ++i) {
            acc0[i] += v0[i]; acc1[i] += v1[i]; acc2[i] += v2[i]; acc3[i] += v3[i];
        }
    };

    if (wv >= 4) dump(wv - 4);
    __syncthreads();
    if (wv < 4) take(wv);
    __syncthreads();
    if (wv == 2 || wv == 3) dump(wv - 2);
    __syncthreads();
    if (wv < 2) take(wv);
    __syncthreads();
    if (wv == 1) dump(0);
    __syncthreads();

    if (wv == 0) {
        take(0);
        float ds = 0.f;
#pragma unroll
        for (int w = 0; w < 8; ++w) ds += denred[w * 32 + r];
        const float inv = 1.f / ds;
        const size_t orow = (size_t)(rbase + r) * OUTF;
#pragma unroll
        for (int fb = 0; fb < 4; ++fb) {
            const f32x16* A = (fb == 0) ? &acc0 : (fb == 1) ? &acc1 : (fb == 2) ? &acc2 : &acc3;
#pragma unroll
            for (int u = 0; u < 4; ++u) {
                f32x4 o;
#pragma unroll
                for (int e = 0; e < 4; ++e) {
                    float v = (*A)[4 * u + e] * inv;
                    o[e] = v > 0.f ? v : expm1f(v);
                }
                *(f32x4*)&out[orow + fb * 32 + 8 * u + 4 * ag] = o;
            }
        }
    }
}

extern "C" void kernel_launch(void* const* d_in, const int* in_sizes, int n_in,
                              void* d_out, int out_size, void* d_ws, size_t ws_size,
                              hipStream_t stream) {
    const float* x     = (const float*)d_in[0];
    const int*   adj   = (const int*)d_in[1];
    const float* W1    = (const float*)d_in[2];
    const float* b1    = (const float*)d_in[3];
    const float* a     = (const float*)d_in[4];
    const float* b_att = (const float*)d_in[5];
    float* out = (float*)d_out;

    char* ws = (char*)d_ws;
    unsigned char* mask8 = (unsigned char*)ws;                 // 8 MB
    bf16* WhbF = (bf16*)(ws + (size_t)8 * 1024 * 1024);        // 2 MB
    float* E1 = (float*)(ws + (size_t)10 * 1024 * 1024);
    float* E2 = E1 + NODES;
    float* F1 = E2 + NODES;
    float* F2 = F1 + NODES;

    hipLaunchKernelGGL(gat_pack_r10, dim3(65536), dim3(256), 0, stream,
                       (const i32x4*)adj, mask8);

    hipLaunchKernelGGL(gat_prep_r10, dim3(NODES / 32), dim3(256), 0, stream,
                       x, W1, b1, a, b_att, WhbF, E1, E2, F1, F2);

    hipLaunchKernelGGL(gat_attn_r10, dim3(NODES / 32), dim3(512), SMEM2_SIZE, stream,
                       (const unsigned long long*)mask8, WhbF, E1, E2, F1, F2, out);
}